// Round 3
// baseline (3855.139 us; speedup 1.0000x reference)
//
#include <hip/hip_runtime.h>

#define BB 16
#define NN 2048
#define NITERS 100

// k = log2(e)/eps, eps = 0.05
#define K2E      28.853900817779268f
#define TWO_K2E  57.707801635558536f
#define INV2K    0.017328679513998632f   // 1/(2k)
#define INV_K2E  0.034657359027997264f
#define INV4K    0.008664339756999316f   // 1/(4k)
#define LMU      (-11.0f)                // log2(1/2048)

#if __has_builtin(__builtin_amdgcn_exp2f)
#define EXP2F(x) __builtin_amdgcn_exp2f(x)
#else
#define EXP2F(x) exp2f(x)
#endif

typedef float v2f __attribute__((ext_vector_type(2)));

// device-coherent (LLC-homed) accessors for the dual arrays
#define DSTORE(p, v) __hip_atomic_store((p), (v), __ATOMIC_RELAXED, __HIP_MEMORY_SCOPE_AGENT)
#define DLOAD(p)     __hip_atomic_load((p), __ATOMIC_RELAXED, __HIP_MEMORY_SCOPE_AGENT)

// R15 wave-autonomous sum-pass: 8 rows x FULL j-range (2048) per wave.
// 32 LLC dual preloads in flight; same packed-f32 body and verified
// butterfly as before; NO pcomb / NO __syncthreads — returns the full
// row-sum on lanes 0..7 (row = rloc + rr).
__device__ __forceinline__ float sumpassW(
    const float* __restrict__ u0, const float* __restrict__ u1,
    const float* __restrict__ u2,
    const float* __restrict__ t0, const float* __restrict__ t1,
    const float* __restrict__ t2, const float* __restrict__ gd,
    int rloc, int lane)
{
    float dv[32];
    #pragma unroll
    for (int s = 0; s < 32; ++s)
        dv[s] = DLOAD(gd + lane + (s << 6));

    v2f xp0[4], xp1[4], xp2[4], acc2[4];
    #pragma unroll
    for (int p = 0; p < 4; ++p) {
        xp0[p] = (v2f){u0[rloc + 2*p] * INV2K, u0[rloc + 2*p + 1] * INV2K};
        xp1[p] = (v2f){u1[rloc + 2*p] * INV2K, u1[rloc + 2*p + 1] * INV2K};
        xp2[p] = (v2f){u2[rloc + 2*p] * INV2K, u2[rloc + 2*p + 1] * INV2K};
        acc2[p] = (v2f){0.f, 0.f};
    }
    #pragma unroll 2
    for (int s = 0; s < 32; ++s) {
        const int p = lane + (s << 6);
        const float a0 = t0[p], a1 = t1[p], a2 = t2[p], ad = dv[s];
        const v2f a0v = (v2f){a0, a0}, a1v = (v2f){a1, a1};
        const v2f a2v = (v2f){a2, a2}, adv = (v2f){ad, ad};
        #pragma unroll
        for (int q = 0; q < 4; ++q) {
            v2f d = __builtin_elementwise_fma(xp0[q], a0v,
                    __builtin_elementwise_fma(xp1[q], a1v,
                    __builtin_elementwise_fma(xp2[q], a2v, adv)));
            acc2[q] += (v2f){EXP2F(d.x), EXP2F(d.y)};
        }
    }
    float acc[8];
    #pragma unroll
    for (int p = 0; p < 4; ++p) { acc[2*p] = acc2[p].x; acc[2*p+1] = acc2[p].y; }
    // multi-value butterfly (verified R3/R5/R8); lanes<8 end with row rr
    const bool b0 = lane & 1, b1 = lane & 2, b2 = lane & 4;
    float v4[4], v2_[2], v1;
    #pragma unroll
    for (int i = 0; i < 4; ++i) {
        float recv = __shfl_xor(b0 ? acc[i] : acc[i+4], 1, 64);
        v4[i] = (b0 ? acc[i+4] : acc[i]) + recv;
    }
    #pragma unroll
    for (int i = 0; i < 2; ++i) {
        float recv = __shfl_xor(b1 ? v4[i] : v4[i+2], 2, 64);
        v2_[i] = (b1 ? v4[i+2] : v4[i]) + recv;
    }
    {
        float recv = __shfl_xor(b2 ? v2_[0] : v2_[1], 4, 64);
        v1 = (b2 ? v2_[1] : v2_[0]) + recv;
    }
    v1 += __shfl_xor(v1, 8, 64);
    v1 += __shfl_xor(v1, 16, 64);
    v1 += __shfl_xor(v1, 32, 64);
    return v1;   // lanes<8: full row-sum for row rloc + rr
}

// Epilogue partial: sum_j P_ij*C_ij, 8 rows x ONE j-half (called twice to
// cap register pressure). UNCHANGED from verified version.
__device__ __forceinline__ float epilG(
    const float* __restrict__ u0, const float* __restrict__ u1,
    const float* __restrict__ u2,
    const float* __restrict__ t0, const float* __restrict__ t1,
    const float* __restrict__ t2, const float* __restrict__ gB,
    float Aval, int rloc, int jh, int lane)
{
    const int jb = (jh << 10) + lane;
    float dv[16];
    #pragma unroll
    for (int s = 0; s < 16; ++s)
        dv[s] = DLOAD(gB + jb + (s << 6));

    float xr0[8], xr1[8], xr2[8], Ak[8], x2k[8];
    #pragma unroll
    for (int k = 0; k < 8; ++k) {
        xr0[k] = u0[rloc + k] * INV2K;
        xr1[k] = u1[rloc + k] * INV2K;
        xr2[k] = u2[rloc + k] * INV2K;
        const int src = ((k & 1) << 2) | (k & 2) | ((k >> 2) & 1);
        Ak[k]  = __shfl(Aval, src, 64);
        x2k[k] = K2E * (xr0[k]*xr0[k] + xr1[k]*xr1[k] + xr2[k]*xr2[k]);
    }
    float acc = 0.f;
    for (int s = 0; s < 16; ++s) {
        const int p = jb + (s << 6);
        const float a0 = t0[p], a1 = t1[p], a2 = t2[p], tb = dv[s];
        const float q2 = (a0*a0 + a1*a1 + a2*a2) * INV4K;   // k|y|^2
        #pragma unroll
        for (int k = 0; k < 8; ++k) {
            float d = fmaf(xr0[k], a0, fmaf(xr1[k], a1, fmaf(xr2[k], a2, tb)));
            float P = EXP2F(d + Ak[k]);                       // exp(logP)
            float C = fmaxf((x2k[k] + q2 - (d - tb)) * INV_K2E, 0.f);
            acc = fmaf(P, C, acc);
        }
    }
    return acc;
}

// R15: wave-autonomous Sinkhorn. 256 blocks x 1024 threads, 1 block/CU.
// block = batch (blk&15) x 128 rows (rb = blk>>4). Each wave owns 8 rows x
// full j. ZERO barriers in the iteration loop:
//   post  = vmcnt(0) drain + LDS counter; last of 16 waves release-stores
//           the block's flag slot.
//   wait  = per-wave 16-lane ballot poll over the batch's 16 block slots.
// Waves drift/stagger, so polls and LLC preload latency of one wave are
// covered by its 3 SIMD-mates' compute. All 16 blocks of a batch share one
// XCD (blk step 16 ≡ 0 mod 8).
__global__ __launch_bounds__(1024) void emd_sinkhornW(
    const float* __restrict__ x, const float* __restrict__ y,
    float* __restrict__ Af, float* __restrict__ Bf,
    int* __restrict__ flags, float* __restrict__ out)
{
    extern __shared__ float S[];     // 6*NN floats = 48 KB
    __shared__ float wsum[16];
    __shared__ int scnt;             // monotonic wave-completion counter

    const int tid  = threadIdx.x;
    const int lane = tid & 63;
    const int w    = tid >> 6;        // 0..15
    const int blk  = blockIdx.x;
    const int b    = blk & 15;        // batch
    const int rb   = blk >> 4;        // 0..15: row-block within batch
    const int base = b * NN;
    const int rloc = rb * 128 + w * 8;
    int* fbase  = flags + b * 64;     // 16 slots x 16 B per batch
    int* myflag = fbase + rb * 4;

    // LDS carve: 6 table slots of NN floats (SoA — conflict-free)
    float *sy0 = S,        *sy1 = S +   NN, *sy2 = S + 2*NN;
    float *sx0 = S + 3*NN, *sx1 = S + 4*NN, *sx2 = S + 5*NN;

    // ---- prologue: stage 2k-scaled tables for own batch ----
    if (tid == 0) scnt = 0;
    #pragma unroll
    for (int v = 0; v < 2; ++v) {
        const int p = tid + (v << 10);
        const float* px = x + 3 * (size_t)(base + p);
        sx0[p] = TWO_K2E * px[0]; sx1[p] = TWO_K2E * px[1]; sx2[p] = TWO_K2E * px[2];
        const float* py = y + 3 * (size_t)(base + p);
        sy0[p] = TWO_K2E * py[0]; sy1[p] = TWO_K2E * py[1]; sy2[p] = TWO_K2E * py[2];
    }
    // ---- prologue: B0-init for own 128 columns ----
    if (tid < 128) {
        const int col = rb * 128 + tid;
        const float* py = y + 3 * (size_t)(base + col);
        const float a = py[0], bb = py[1], c = py[2];
        DSTORE(&Bf[base + col], -K2E * (a*a + bb*bb + c*c));
    }
    __syncthreads();                  // drains tables + B-init (vmcnt 0)
    if (tid == 0)
        __hip_atomic_store(myflag, 1, __ATOMIC_RELEASE, __HIP_MEMORY_SCOPE_AGENT);

    // per-wave wait: all 16 blocks of own batch posted >= tgt
    #define WAITF(tgt) do {                                                     \
        for (;;) {                                                              \
            int vv = (lane < 16)                                                \
                ? __hip_atomic_load(fbase + lane * 4, __ATOMIC_RELAXED,         \
                                    __HIP_MEMORY_SCOPE_AGENT)                   \
                : 0x7fffffff;                                                   \
            if (__ballot(vv >= (tgt)) == ~0ULL) break;                          \
            __builtin_amdgcn_s_sleep(1);                                        \
        }                                                                       \
        asm volatile("" ::: "memory");                                          \
    } while (0)

    // per-wave post of phase value v: drain own stores, count in LDS;
    // the 16th wave of this phase publishes the block flag.
    #define POSTF(v) do {                                                       \
        asm volatile("s_waitcnt vmcnt(0)" ::: "memory");                        \
        if (lane == 0) {                                                        \
            int r = __hip_atomic_fetch_add(&scnt, 1, __ATOMIC_ACQ_REL,          \
                                           __HIP_MEMORY_SCOPE_WORKGROUP);       \
            if (r + 1 == 16 * ((v) - 1))                                        \
                __hip_atomic_store(myflag, (v), __ATOMIC_RELEASE,               \
                                   __HIP_MEMORY_SCOPE_AGENT);                   \
        }                                                                       \
    } while (0)

    const int rr = ((lane & 1) << 2) | (lane & 2) | ((lane >> 2) & 1);
    float Aval = 0.f;

    for (int it = 0; it < NITERS; ++it) {
        // ---- f-phase: dual = Bf (g of it-1 / init) ----
        WAITF(2 * it + 1);
        {
            float Sc = sumpassW(sx0, sx1, sx2, sy0, sy1, sy2, Bf + base,
                                rloc, lane);
            Aval = LMU - __log2f(Sc);
            if (lane < 8) DSTORE(&Af[base + rloc + rr], Aval);
        }
        POSTF(2 * it + 2);
        // ---- g-phase: dual = Af ----
        WAITF(2 * it + 2);
        {
            float Sc = sumpassW(sy0, sy1, sy2, sx0, sx1, sx2, Af + base,
                                rloc, lane);
            if (lane < 8)
                DSTORE(&Bf[base + rloc + rr], LMU - __log2f(Sc));
        }
        POSTF(2 * it + 3);
    }
    WAITF(2 * NITERS + 1);            // final Bf complete across the batch

    // ---- epilogue: own 8 rows (per wave), both j-halves ----
    {
        float s = epilG(sx0, sx1, sx2, sy0, sy1, sy2, Bf + base,
                        Aval, rloc, 0, lane)
                + epilG(sx0, sx1, sx2, sy0, sy1, sy2, Bf + base,
                        Aval, rloc, 1, lane);
        #pragma unroll
        for (int m = 32; m > 0; m >>= 1) s += __shfl_xor(s, m, 64);
        if (lane == 0) wsum[w] = s;
        __syncthreads();
        if (tid == 0) {
            float t = 0.f;
            #pragma unroll
            for (int i = 0; i < 16; ++i) t += wsum[i];
            atomicAdd(out, t * (1.0f / (float)BB));
        }
    }
    #undef WAITF
    #undef POSTF
}

// ---- verified R12 two-batch kernel, kept verbatim as launch fallback ----
__device__ __forceinline__ float sumpassG(
    const float* __restrict__ u0, const float* __restrict__ u1,
    const float* __restrict__ u2,
    const float* __restrict__ t0, const float* __restrict__ t1,
    const float* __restrict__ t2, const float* __restrict__ gd,
    int rloc, int jh, int lane, int w, float* pcomb)
{
    const int jb = (jh << 10) + lane;
    float dv[16];
    #pragma unroll
    for (int s = 0; s < 16; ++s)
        dv[s] = DLOAD(gd + jb + (s << 6));

    v2f xp0[4], xp1[4], xp2[4], acc2[4];
    #pragma unroll
    for (int p = 0; p < 4; ++p) {
        xp0[p] = (v2f){u0[rloc + 2*p] * INV2K, u0[rloc + 2*p + 1] * INV2K};
        xp1[p] = (v2f){u1[rloc + 2*p] * INV2K, u1[rloc + 2*p + 1] * INV2K};
        xp2[p] = (v2f){u2[rloc + 2*p] * INV2K, u2[rloc + 2*p + 1] * INV2K};
        acc2[p] = (v2f){0.f, 0.f};
    }
    #pragma unroll 2
    for (int s = 0; s < 16; ++s) {
        const int p = jb + (s << 6);
        const float a0 = t0[p], a1 = t1[p], a2 = t2[p], ad = dv[s];
        const v2f a0v = (v2f){a0, a0}, a1v = (v2f){a1, a1};
        const v2f a2v = (v2f){a2, a2}, adv = (v2f){ad, ad};
        #pragma unroll
        for (int q = 0; q < 4; ++q) {
            v2f d = __builtin_elementwise_fma(xp0[q], a0v,
                    __builtin_elementwise_fma(xp1[q], a1v,
                    __builtin_elementwise_fma(xp2[q], a2v, adv)));
            acc2[q] += (v2f){EXP2F(d.x), EXP2F(d.y)};
        }
    }
    float acc[8];
    #pragma unroll
    for (int p = 0; p < 4; ++p) { acc[2*p] = acc2[p].x; acc[2*p+1] = acc2[p].y; }
    const bool b0 = lane & 1, b1 = lane & 2, b2 = lane & 4;
    float v4[4], v2_[2], v1;
    #pragma unroll
    for (int i = 0; i < 4; ++i) {
        float recv = __shfl_xor(b0 ? acc[i] : acc[i+4], 1, 64);
        v4[i] = (b0 ? acc[i+4] : acc[i]) + recv;
    }
    #pragma unroll
    for (int i = 0; i < 2; ++i) {
        float recv = __shfl_xor(b1 ? v4[i] : v4[i+2], 2, 64);
        v2_[i] = (b1 ? v4[i+2] : v4[i]) + recv;
    }
    {
        float recv = __shfl_xor(b2 ? v2_[0] : v2_[1], 4, 64);
        v1 = (b2 ? v2_[1] : v2_[0]) + recv;
    }
    v1 += __shfl_xor(v1, 8, 64);
    v1 += __shfl_xor(v1, 16, 64);
    v1 += __shfl_xor(v1, 32, 64);
    const int rr = ((lane & 1) << 2) | (lane & 2) | ((lane >> 2) & 1);
    if (lane < 8) pcomb[w * 8 + rr] = v1;
    __syncthreads();
    float S = 0.f;
    if (lane < 8) S = v1 + pcomb[(w ^ 1) * 8 + rr];
    return S;
}

__global__ __launch_bounds__(1024) void emd_sinkhorn2(
    const float* __restrict__ x, const float* __restrict__ y,
    float* __restrict__ Af, float* __restrict__ Bf,
    int* __restrict__ flags, float* __restrict__ out)
{
    extern __shared__ float S[];     // 12*NN floats = 96 KB
    __shared__ float pcomb[16 * 8];
    __shared__ float wsum[16];

    const int tid  = threadIdx.x;
    const int lane = tid & 63;
    const int w    = tid >> 6;
    const int pr   = w >> 1;
    const int jh   = w & 1;
    const int blk  = blockIdx.x;
    const int pair = blk & 7;
    const int q    = blk >> 3;
    const int b0   = pair * 2, b1 = b0 + 1;
    const int base0 = b0 * NN, base1 = b1 * NN;
    const int rloc  = q * 64 + pr * 8;
    int* f0 = flags + 4096 + b0 * 128;
    int* f1 = flags + 4096 + b1 * 128;

    float *sy00 = S,            *sy10 = S +  1*NN, *sy20 = S +  2*NN;
    float *sx00 = S +  3*NN,    *sx10 = S +  4*NN, *sx20 = S +  5*NN;
    float *sy01 = S +  6*NN,    *sy11 = S +  7*NN, *sy21 = S +  8*NN;
    float *sx01 = S +  9*NN,    *sx11 = S + 10*NN, *sx21 = S + 11*NN;

    #pragma unroll
    for (int v = 0; v < 2; ++v) {
        const int p = tid + (v << 10);
        {
            const float* px = x + 3 * (size_t)(base0 + p);
            sx00[p] = TWO_K2E * px[0]; sx10[p] = TWO_K2E * px[1]; sx20[p] = TWO_K2E * px[2];
            const float* py = y + 3 * (size_t)(base0 + p);
            sy00[p] = TWO_K2E * py[0]; sy10[p] = TWO_K2E * py[1]; sy20[p] = TWO_K2E * py[2];
        }
        {
            const float* px = x + 3 * (size_t)(base1 + p);
            sx01[p] = TWO_K2E * px[0]; sx11[p] = TWO_K2E * px[1]; sx21[p] = TWO_K2E * px[2];
            const float* py = y + 3 * (size_t)(base1 + p);
            sy01[p] = TWO_K2E * py[0]; sy11[p] = TWO_K2E * py[1]; sy21[p] = TWO_K2E * py[2];
        }
    }
    if (tid < 128) {
        const int bb  = tid >> 6;
        const int col = q * 64 + (tid & 63);
        const int bs  = bb ? base1 : base0;
        const float* py = y + 3 * (size_t)(bs + col);
        const float a = py[0], b = py[1], c = py[2];
        DSTORE(&Bf[bs + col], -K2E * (a*a + b*b + c*c));
    }
    __syncthreads();
    if (tid == 0) {
        __hip_atomic_store(f0 + q * 4, 1, __ATOMIC_RELEASE, __HIP_MEMORY_SCOPE_AGENT);
        __hip_atomic_store(f1 + q * 4, 1, __ATOMIC_RELEASE, __HIP_MEMORY_SCOPE_AGENT);
    }

    const int rr = ((lane & 1) << 2) | (lane & 2) | ((lane >> 2) & 1);

    #define PW2(pslot, pval, warr, tgt) do { __syncthreads();                   \
        if (tid == 0)                                                           \
            __hip_atomic_store((pslot), (pval), __ATOMIC_RELEASE,               \
                               __HIP_MEMORY_SCOPE_AGENT);                       \
        if (w == 0) {                                                           \
            for (;;) {                                                          \
                int vv = (lane < 32)                                            \
                    ? __hip_atomic_load((warr) + lane * 4, __ATOMIC_RELAXED,    \
                                        __HIP_MEMORY_SCOPE_AGENT)               \
                    : 0x7fffffff;                                               \
                if (__ballot(vv >= (tgt)) == ~0ULL) break;                      \
                __builtin_amdgcn_s_sleep(1);                                    \
            }                                                                   \
        }                                                                       \
        __syncthreads(); } while (0)

    #define WONLY2(warr, tgt) do { __syncthreads();                             \
        if (w == 0) {                                                           \
            for (;;) {                                                          \
                int vv = (lane < 32)                                            \
                    ? __hip_atomic_load((warr) + lane * 4, __ATOMIC_RELAXED,    \
                                        __HIP_MEMORY_SCOPE_AGENT)               \
                    : 0x7fffffff;                                               \
                if (__ballot(vv >= (tgt)) == ~0ULL) break;                      \
                __builtin_amdgcn_s_sleep(1);                                    \
            }                                                                   \
        }                                                                       \
        __syncthreads(); } while (0)

    WONLY2(f0, 1);

    float Aval0 = 0.f, Aval1 = 0.f;

    for (int it = 0; it < NITERS; ++it) {
        {
            float Sc = sumpassG(sx00, sx10, sx20, sy00, sy10, sy20, Bf + base0,
                                rloc, jh, lane, w, pcomb);
            Aval0 = LMU - __log2f(Sc);
            if (lane < 8 && jh == 0) DSTORE(&Af[base0 + rloc + rr], Aval0);
        }
        PW2(f0 + q * 4, 2 * it + 2, f1, 2 * it + 1);
        {
            float Sc = sumpassG(sx01, sx11, sx21, sy01, sy11, sy21, Bf + base1,
                                rloc, jh, lane, w, pcomb);
            Aval1 = LMU - __log2f(Sc);
            if (lane < 8 && jh == 0) DSTORE(&Af[base1 + rloc + rr], Aval1);
        }
        PW2(f1 + q * 4, 2 * it + 2, f0, 2 * it + 2);
        {
            float Sc = sumpassG(sy00, sy10, sy20, sx00, sx10, sx20, Af + base0,
                                rloc, jh, lane, w, pcomb);
            if (lane < 8 && jh == 0)
                DSTORE(&Bf[base0 + rloc + rr], LMU - __log2f(Sc));
        }
        PW2(f0 + q * 4, 2 * it + 3, f1, 2 * it + 2);
        {
            float Sc = sumpassG(sy01, sy11, sy21, sx01, sx11, sx21, Af + base1,
                                rloc, jh, lane, w, pcomb);
            if (lane < 8 && jh == 0)
                DSTORE(&Bf[base1 + rloc + rr], LMU - __log2f(Sc));
        }
        PW2(f1 + q * 4, 2 * it + 3, f0, 2 * it + 3);
    }
    WONLY2(f1, 2 * NITERS + 1);

    {
        float s = epilG(sx00, sx10, sx20, sy00, sy10, sy20, Bf + base0,
                        Aval0, rloc, jh, lane)
                + epilG(sx01, sx11, sx21, sy01, sy11, sy21, Bf + base1,
                        Aval1, rloc, jh, lane);
        #pragma unroll
        for (int m = 32; m > 0; m >>= 1) s += __shfl_xor(s, m, 64);
        if (lane == 0) wsum[w] = s;
        __syncthreads();
        if (tid == 0) {
            float t = 0.f;
            #pragma unroll
            for (int i = 0; i < 16; ++i) t += wsum[i];
            atomicAdd(out, t * (1.0f / (float)BB));
        }
    }
    #undef PW2
    #undef WONLY2
}

extern "C" void kernel_launch(void* const* d_in, const int* in_sizes, int n_in,
                              void* d_out, int out_size, void* d_ws, size_t ws_size,
                              hipStream_t stream) {
    const float* x = (const float*)d_in[0];
    const float* y = (const float*)d_in[1];
    float* out = (float*)d_out;
    char* ws = (char*)d_ws;

    int*   flags = (int*)ws;                                 // 8 KB (W uses 4 KB, fallback upper 4 KB)
    float* Af    = (float*)(ws + 8192);                      // 128 KB
    float* Bf    = (float*)(ws + 8192 + (size_t)BB*NN*sizeof(float));

    hipMemsetAsync(flags, 0, 8192, stream);
    hipMemsetAsync(out, 0, sizeof(float), stream);

    void* args[] = {(void*)&x, (void*)&y, (void*)&Af, (void*)&Bf,
                    (void*)&flags, (void*)&out};

    // Preferred: wave-autonomous kernel, 256 blocks (1/CU), 48 KB LDS.
    const size_t shmemW = (size_t)6 * NN * sizeof(float);
    hipFuncSetAttribute((const void*)emd_sinkhornW,
                        hipFuncAttributeMaxDynamicSharedMemorySize, (int)shmemW);
    hipError_t e = hipLaunchCooperativeKernel((const void*)emd_sinkhornW,
                                              dim3(256), dim3(1024),
                                              args, shmemW, stream);
    if (e != hipSuccess) {
        // Fallback: verified two-batch kernel (256 blocks, 96 KB LDS).
        const size_t shmem2 = (size_t)12 * NN * sizeof(float);
        hipFuncSetAttribute((const void*)emd_sinkhorn2,
                            hipFuncAttributeMaxDynamicSharedMemorySize, (int)shmem2);
        hipError_t e2 = hipLaunchCooperativeKernel((const void*)emd_sinkhorn2,
                                                   dim3(256), dim3(1024),
                                                   args, shmem2, stream);
        if (e2 != hipSuccess) {
            hipLaunchKernelGGL(emd_sinkhorn2, dim3(256), dim3(1024), shmem2,
                               stream, x, y, Af, Bf, flags, out);
        }
    }
}

// Round 4
// 3793.853 us; speedup vs baseline: 1.0162x; 1.0162x over previous
//
#include <hip/hip_runtime.h>

#define BB 16
#define NN 2048
#define NITERS 100

// k = log2(e)/eps, eps = 0.05
#define K2E      28.853900817779268f
#define TWO_K2E  57.707801635558536f
#define INV2K    0.017328679513998632f   // 1/(2k)
#define INV_K2E  0.034657359027997264f
#define INV4K    0.008664339756999316f   // 1/(4k)
#define LMU      (-11.0f)                // log2(1/2048)

#if __has_builtin(__builtin_amdgcn_exp2f)
#define EXP2F(x) __builtin_amdgcn_exp2f(x)
#else
#define EXP2F(x) exp2f(x)
#endif

typedef float v2f __attribute__((ext_vector_type(2)));

// device-coherent (LLC-homed) accessors for the dual arrays
#define DSTORE(p, v) __hip_atomic_store((p), (v), __ATOMIC_RELAXED, __HIP_MEMORY_SCOPE_AGENT)
#define DLOAD(p)     __hip_atomic_load((p), __ATOMIC_RELAXED, __HIP_MEMORY_SCOPE_AGENT)

// R16 sum-pass with PAIR-LOCAL combine (no block barrier): 8 rows/wave,
// own j-half. Partials exchanged through phase-parity double-buffered
// pcomb + per-wave LDS seq handshake (release/acquire, workgroup scope).
// Safety: intra-block drift is bounded to <2 phases by the flag gating
// (each phase-entry wait requires the own-block post of phase p-2), so
// parity double-buffering + the seq ordering make reuse race-free.
__device__ __forceinline__ float sumpassP(
    const float* __restrict__ u0, const float* __restrict__ u1,
    const float* __restrict__ u2,
    const float* __restrict__ t0, const float* __restrict__ t1,
    const float* __restrict__ t2, const float* __restrict__ gd,
    int rloc, int jh, int lane, int w, float* pcomb, int* pseq, int ph)
{
    const int jb = (jh << 10) + lane;
    float dv[16];
    #pragma unroll
    for (int s = 0; s < 16; ++s)
        dv[s] = DLOAD(gd + jb + (s << 6));

    v2f xp0[4], xp1[4], xp2[4], acc2[4];
    #pragma unroll
    for (int p = 0; p < 4; ++p) {
        xp0[p] = (v2f){u0[rloc + 2*p] * INV2K, u0[rloc + 2*p + 1] * INV2K};
        xp1[p] = (v2f){u1[rloc + 2*p] * INV2K, u1[rloc + 2*p + 1] * INV2K};
        xp2[p] = (v2f){u2[rloc + 2*p] * INV2K, u2[rloc + 2*p + 1] * INV2K};
        acc2[p] = (v2f){0.f, 0.f};
    }
    #pragma unroll 2
    for (int s = 0; s < 16; ++s) {
        const int p = jb + (s << 6);
        const float a0 = t0[p], a1 = t1[p], a2 = t2[p], ad = dv[s];
        const v2f a0v = (v2f){a0, a0}, a1v = (v2f){a1, a1};
        const v2f a2v = (v2f){a2, a2}, adv = (v2f){ad, ad};
        #pragma unroll
        for (int q = 0; q < 4; ++q) {
            v2f d = __builtin_elementwise_fma(xp0[q], a0v,
                    __builtin_elementwise_fma(xp1[q], a1v,
                    __builtin_elementwise_fma(xp2[q], a2v, adv)));
            acc2[q] += (v2f){EXP2F(d.x), EXP2F(d.y)};
        }
    }
    float acc[8];
    #pragma unroll
    for (int p = 0; p < 4; ++p) { acc[2*p] = acc2[p].x; acc[2*p+1] = acc2[p].y; }
    // multi-value butterfly (verified R3/R5/R8); lanes<8 end with row rr
    const bool b0 = lane & 1, b1 = lane & 2, b2 = lane & 4;
    float v4[4], v2_[2], v1;
    #pragma unroll
    for (int i = 0; i < 4; ++i) {
        float recv = __shfl_xor(b0 ? acc[i] : acc[i+4], 1, 64);
        v4[i] = (b0 ? acc[i+4] : acc[i]) + recv;
    }
    #pragma unroll
    for (int i = 0; i < 2; ++i) {
        float recv = __shfl_xor(b1 ? v4[i] : v4[i+2], 2, 64);
        v2_[i] = (b1 ? v4[i+2] : v4[i]) + recv;
    }
    {
        float recv = __shfl_xor(b2 ? v2_[0] : v2_[1], 4, 64);
        v1 = (b2 ? v2_[1] : v2_[0]) + recv;
    }
    v1 += __shfl_xor(v1, 8, 64);
    v1 += __shfl_xor(v1, 16, 64);
    v1 += __shfl_xor(v1, 32, 64);
    const int rr = ((lane & 1) << 2) | (lane & 2) | ((lane >> 2) & 1);
    const int pb = (ph & 1) << 7;                 // parity double-buffer
    if (lane < 8) pcomb[pb + w * 8 + rr] = v1;
    if (lane == 0)
        __hip_atomic_store(&pseq[w], ph, __ATOMIC_RELEASE,
                           __HIP_MEMORY_SCOPE_WORKGROUP);
    while (__hip_atomic_load(&pseq[w ^ 1], __ATOMIC_ACQUIRE,
                             __HIP_MEMORY_SCOPE_WORKGROUP) < ph) {}
    float S = 0.f;
    if (lane < 8) S = v1 + pcomb[pb + (w ^ 1) * 8 + rr];
    return S;
}

// Epilogue partial: sum_j P_ij*C_ij, 8 rows x own j-half. (UNCHANGED.)
__device__ __forceinline__ float epilG(
    const float* __restrict__ u0, const float* __restrict__ u1,
    const float* __restrict__ u2,
    const float* __restrict__ t0, const float* __restrict__ t1,
    const float* __restrict__ t2, const float* __restrict__ gB,
    float Aval, int rloc, int jh, int lane)
{
    const int jb = (jh << 10) + lane;
    float dv[16];
    #pragma unroll
    for (int s = 0; s < 16; ++s)
        dv[s] = DLOAD(gB + jb + (s << 6));

    float xr0[8], xr1[8], xr2[8], Ak[8], x2k[8];
    #pragma unroll
    for (int k = 0; k < 8; ++k) {
        xr0[k] = u0[rloc + k] * INV2K;
        xr1[k] = u1[rloc + k] * INV2K;
        xr2[k] = u2[rloc + k] * INV2K;
        const int src = ((k & 1) << 2) | (k & 2) | ((k >> 2) & 1);
        Ak[k]  = __shfl(Aval, src, 64);
        x2k[k] = K2E * (xr0[k]*xr0[k] + xr1[k]*xr1[k] + xr2[k]*xr2[k]);
    }
    float acc = 0.f;
    for (int s = 0; s < 16; ++s) {
        const int p = jb + (s << 6);
        const float a0 = t0[p], a1 = t1[p], a2 = t2[p], tb = dv[s];
        const float q2 = (a0*a0 + a1*a1 + a2*a2) * INV4K;   // k|y|^2
        #pragma unroll
        for (int k = 0; k < 8; ++k) {
            float d = fmaf(xr0[k], a0, fmaf(xr1[k], a1, fmaf(xr2[k], a2, tb)));
            float P = EXP2F(d + Ak[k]);                       // exp(logP)
            float C = fmaxf((x2k[k] + q2 - (d - tb)) * INV_K2E, 0.f);
            acc = fmaf(P, C, acc);
        }
    }
    return acc;
}

// R16: R12's proven two-batch 4-phase slack schedule with ZERO block
// barriers in the loop. 256 blocks x 1024 threads (1/CU). Per phase:
//   combine : pair-local LDS handshake (sumpassP)
//   post    : per-wave vmcnt(0) drain + mod-2 LDS phase counter; 16th
//             wave resets the counter then release-posts the flag.
//             (mod-2 + reset because slack permits 1 phase of intra-block
//             drift; a cumulative counter would post early.)
//   wait    : per-wave 32-slot poll + ballot (HW-validated in R15).
// Every wait target is posted >= 1 full phase earlier (R12's slack).
__global__ __launch_bounds__(1024) void emd_sinkhornF(
    const float* __restrict__ x, const float* __restrict__ y,
    float* __restrict__ Af, float* __restrict__ Bf,
    int* __restrict__ flags, float* __restrict__ out)
{
    extern __shared__ float S[];     // 12*NN floats = 96 KB
    __shared__ float pcomb[2 * 128]; // phase-parity double buffer
    __shared__ float wsum[16];
    __shared__ int pseq[16];
    __shared__ int scnt2[2];

    const int tid  = threadIdx.x;
    const int lane = tid & 63;
    const int w    = tid >> 6;        // 0..15
    const int pr   = w >> 1;          // wave-pair 0..7
    const int jh   = w & 1;           // j-half
    const int blk  = blockIdx.x;
    const int pair = blk & 7;         // = XCD id under round-robin
    const int q    = blk >> 3;        // 0..31: row-slice within pair
    const int b0   = pair * 2, b1 = b0 + 1;
    const int base0 = b0 * NN, base1 = b1 * NN;
    const int rloc  = q * 64 + pr * 8;
    int* f0 = flags + b0 * 128;       // 32 slots x 16 B per batch
    int* f1 = flags + b1 * 128;

    float *sy00 = S,            *sy10 = S +  1*NN, *sy20 = S +  2*NN;
    float *sx00 = S +  3*NN,    *sx10 = S +  4*NN, *sx20 = S +  5*NN;
    float *sy01 = S +  6*NN,    *sy11 = S +  7*NN, *sy21 = S +  8*NN;
    float *sx01 = S +  9*NN,    *sx11 = S + 10*NN, *sx21 = S + 11*NN;

    if (tid < 16) pseq[tid] = 0;
    if (tid < 2)  scnt2[tid] = 0;

    // ---- prologue: stage 2k-scaled tables ----
    #pragma unroll
    for (int v = 0; v < 2; ++v) {
        const int p = tid + (v << 10);
        {
            const float* px = x + 3 * (size_t)(base0 + p);
            sx00[p] = TWO_K2E * px[0]; sx10[p] = TWO_K2E * px[1]; sx20[p] = TWO_K2E * px[2];
            const float* py = y + 3 * (size_t)(base0 + p);
            sy00[p] = TWO_K2E * py[0]; sy10[p] = TWO_K2E * py[1]; sy20[p] = TWO_K2E * py[2];
        }
        {
            const float* px = x + 3 * (size_t)(base1 + p);
            sx01[p] = TWO_K2E * px[0]; sx11[p] = TWO_K2E * px[1]; sx21[p] = TWO_K2E * px[2];
            const float* py = y + 3 * (size_t)(base1 + p);
            sy01[p] = TWO_K2E * py[0]; sy11[p] = TWO_K2E * py[1]; sy21[p] = TWO_K2E * py[2];
        }
    }
    // ---- prologue: B0-init for own 64 columns of both batches ----
    if (tid < 128) {
        const int bb  = tid >> 6;
        const int col = q * 64 + (tid & 63);
        const int bs  = bb ? base1 : base0;
        const float* py = y + 3 * (size_t)(bs + col);
        const float a = py[0], b = py[1], c = py[2];
        DSTORE(&Bf[bs + col], -K2E * (a*a + b*b + c*c));
    }
    __syncthreads();                  // drains tables + B-init (vmcnt 0)
    if (tid == 0) {
        __hip_atomic_store(f0 + q * 4, 1, __ATOMIC_RELEASE, __HIP_MEMORY_SCOPE_AGENT);
        __hip_atomic_store(f1 + q * 4, 1, __ATOMIC_RELEASE, __HIP_MEMORY_SCOPE_AGENT);
    }

    // per-wave wait: all 32 blocks of the pair posted >= tgt in warr
    #define WAITW(warr, tgt) do {                                               \
        for (;;) {                                                              \
            int vv = (lane < 32)                                                \
                ? __hip_atomic_load((warr) + lane * 4, __ATOMIC_RELAXED,        \
                                    __HIP_MEMORY_SCOPE_AGENT)                   \
                : 0x7fffffff;                                                   \
            if (__ballot(vv >= (tgt)) == ~0ULL) break;                          \
            __builtin_amdgcn_s_sleep(1);                                        \
        }                                                                       \
        asm volatile("" ::: "memory");                                          \
    } while (0)

    // per-wave post for global phase p (1..400): drain stores, count on
    // the mod-2 counter; 16th wave resets counter (for p+2) then posts.
    #define POSTW(slot, val, p) do {                                            \
        asm volatile("s_waitcnt vmcnt(0)" ::: "memory");                        \
        if (lane == 0) {                                                        \
            int r = __hip_atomic_fetch_add(&scnt2[(p) & 1], 1, __ATOMIC_ACQ_REL,\
                                           __HIP_MEMORY_SCOPE_WORKGROUP);       \
            if (r == 15) {                                                      \
                __hip_atomic_store(&scnt2[(p) & 1], 0, __ATOMIC_RELAXED,        \
                                   __HIP_MEMORY_SCOPE_WORKGROUP);               \
                __hip_atomic_store((slot), (val), __ATOMIC_RELEASE,             \
                                   __HIP_MEMORY_SCOPE_AGENT);                   \
            }                                                                   \
        }                                                                       \
    } while (0)

    const int rr = ((lane & 1) << 2) | (lane & 2) | ((lane >> 2) & 1);
    float Aval0 = 0.f, Aval1 = 0.f;

    for (int it = 0; it < NITERS; ++it) {
        // ---- fA0 (phase 4it+1): consumes Bf0, posted >=1 phase ago ----
        WAITW(f0, 2 * it + 1);
        {
            float Sc = sumpassP(sx00, sx10, sx20, sy00, sy10, sy20, Bf + base0,
                                rloc, jh, lane, w, pcomb, pseq, 4 * it + 1);
            Aval0 = LMU - __log2f(Sc);
            if (lane < 8 && jh == 0) DSTORE(&Af[base0 + rloc + rr], Aval0);
        }
        POSTW(f0 + q * 4, 2 * it + 2, 4 * it + 1);
        // ---- fA1 (phase 4it+2) ----
        WAITW(f1, 2 * it + 1);
        {
            float Sc = sumpassP(sx01, sx11, sx21, sy01, sy11, sy21, Bf + base1,
                                rloc, jh, lane, w, pcomb, pseq, 4 * it + 2);
            Aval1 = LMU - __log2f(Sc);
            if (lane < 8 && jh == 0) DSTORE(&Af[base1 + rloc + rr], Aval1);
        }
        POSTW(f1 + q * 4, 2 * it + 2, 4 * it + 2);
        // ---- gB0 (phase 4it+3) ----
        WAITW(f0, 2 * it + 2);
        {
            float Sc = sumpassP(sy00, sy10, sy20, sx00, sx10, sx20, Af + base0,
                                rloc, jh, lane, w, pcomb, pseq, 4 * it + 3);
            if (lane < 8 && jh == 0)
                DSTORE(&Bf[base0 + rloc + rr], LMU - __log2f(Sc));
        }
        POSTW(f0 + q * 4, 2 * it + 3, 4 * it + 3);
        // ---- gB1 (phase 4it+4) ----
        WAITW(f1, 2 * it + 2);
        {
            float Sc = sumpassP(sy01, sy11, sy21, sx01, sx11, sx21, Af + base1,
                                rloc, jh, lane, w, pcomb, pseq, 4 * it + 4);
            if (lane < 8 && jh == 0)
                DSTORE(&Bf[base1 + rloc + rr], LMU - __log2f(Sc));
        }
        POSTW(f1 + q * 4, 2 * it + 3, 4 * it + 4);
    }
    WAITW(f0, 2 * NITERS + 1);        // final Bf0
    WAITW(f1, 2 * NITERS + 1);        // final Bf1

    // ---- epilogue: own 64 rows of each batch, own j-half ----
    {
        float s = epilG(sx00, sx10, sx20, sy00, sy10, sy20, Bf + base0,
                        Aval0, rloc, jh, lane)
                + epilG(sx01, sx11, sx21, sy01, sy11, sy21, Bf + base1,
                        Aval1, rloc, jh, lane);
        #pragma unroll
        for (int m = 32; m > 0; m >>= 1) s += __shfl_xor(s, m, 64);
        if (lane == 0) wsum[w] = s;
        __syncthreads();
        if (tid == 0) {
            float t = 0.f;
            #pragma unroll
            for (int i = 0; i < 16; ++i) t += wsum[i];
            atomicAdd(out, t * (1.0f / (float)BB));
        }
    }
    #undef WAITW
    #undef POSTW
}

// ---- verified R12 two-batch kernel, kept as launch fallback ----
__device__ __forceinline__ float sumpassG(
    const float* __restrict__ u0, const float* __restrict__ u1,
    const float* __restrict__ u2,
    const float* __restrict__ t0, const float* __restrict__ t1,
    const float* __restrict__ t2, const float* __restrict__ gd,
    int rloc, int jh, int lane, int w, float* pcomb)
{
    const int jb = (jh << 10) + lane;
    float dv[16];
    #pragma unroll
    for (int s = 0; s < 16; ++s)
        dv[s] = DLOAD(gd + jb + (s << 6));

    v2f xp0[4], xp1[4], xp2[4], acc2[4];
    #pragma unroll
    for (int p = 0; p < 4; ++p) {
        xp0[p] = (v2f){u0[rloc + 2*p] * INV2K, u0[rloc + 2*p + 1] * INV2K};
        xp1[p] = (v2f){u1[rloc + 2*p] * INV2K, u1[rloc + 2*p + 1] * INV2K};
        xp2[p] = (v2f){u2[rloc + 2*p] * INV2K, u2[rloc + 2*p + 1] * INV2K};
        acc2[p] = (v2f){0.f, 0.f};
    }
    #pragma unroll 2
    for (int s = 0; s < 16; ++s) {
        const int p = jb + (s << 6);
        const float a0 = t0[p], a1 = t1[p], a2 = t2[p], ad = dv[s];
        const v2f a0v = (v2f){a0, a0}, a1v = (v2f){a1, a1};
        const v2f a2v = (v2f){a2, a2}, adv = (v2f){ad, ad};
        #pragma unroll
        for (int q = 0; q < 4; ++q) {
            v2f d = __builtin_elementwise_fma(xp0[q], a0v,
                    __builtin_elementwise_fma(xp1[q], a1v,
                    __builtin_elementwise_fma(xp2[q], a2v, adv)));
            acc2[q] += (v2f){EXP2F(d.x), EXP2F(d.y)};
        }
    }
    float acc[8];
    #pragma unroll
    for (int p = 0; p < 4; ++p) { acc[2*p] = acc2[p].x; acc[2*p+1] = acc2[p].y; }
    const bool b0 = lane & 1, b1 = lane & 2, b2 = lane & 4;
    float v4[4], v2_[2], v1;
    #pragma unroll
    for (int i = 0; i < 4; ++i) {
        float recv = __shfl_xor(b0 ? acc[i] : acc[i+4], 1, 64);
        v4[i] = (b0 ? acc[i+4] : acc[i]) + recv;
    }
    #pragma unroll
    for (int i = 0; i < 2; ++i) {
        float recv = __shfl_xor(b1 ? v4[i] : v4[i+2], 2, 64);
        v2_[i] = (b1 ? v4[i+2] : v4[i]) + recv;
    }
    {
        float recv = __shfl_xor(b2 ? v2_[0] : v2_[1], 4, 64);
        v1 = (b2 ? v2_[1] : v2_[0]) + recv;
    }
    v1 += __shfl_xor(v1, 8, 64);
    v1 += __shfl_xor(v1, 16, 64);
    v1 += __shfl_xor(v1, 32, 64);
    const int rr = ((lane & 1) << 2) | (lane & 2) | ((lane >> 2) & 1);
    if (lane < 8) pcomb[w * 8 + rr] = v1;
    __syncthreads();
    float S = 0.f;
    if (lane < 8) S = v1 + pcomb[(w ^ 1) * 8 + rr];
    return S;
}

__global__ __launch_bounds__(1024) void emd_sinkhorn2(
    const float* __restrict__ x, const float* __restrict__ y,
    float* __restrict__ Af, float* __restrict__ Bf,
    int* __restrict__ flags, float* __restrict__ out)
{
    extern __shared__ float S[];     // 12*NN floats = 96 KB
    __shared__ float pcomb[16 * 8];
    __shared__ float wsum[16];

    const int tid  = threadIdx.x;
    const int lane = tid & 63;
    const int w    = tid >> 6;
    const int pr   = w >> 1;
    const int jh   = w & 1;
    const int blk  = blockIdx.x;
    const int pair = blk & 7;
    const int q    = blk >> 3;
    const int b0   = pair * 2, b1 = b0 + 1;
    const int base0 = b0 * NN, base1 = b1 * NN;
    const int rloc  = q * 64 + pr * 8;
    int* f0 = flags + b0 * 128;
    int* f1 = flags + b1 * 128;

    float *sy00 = S,            *sy10 = S +  1*NN, *sy20 = S +  2*NN;
    float *sx00 = S +  3*NN,    *sx10 = S +  4*NN, *sx20 = S +  5*NN;
    float *sy01 = S +  6*NN,    *sy11 = S +  7*NN, *sy21 = S +  8*NN;
    float *sx01 = S +  9*NN,    *sx11 = S + 10*NN, *sx21 = S + 11*NN;

    #pragma unroll
    for (int v = 0; v < 2; ++v) {
        const int p = tid + (v << 10);
        {
            const float* px = x + 3 * (size_t)(base0 + p);
            sx00[p] = TWO_K2E * px[0]; sx10[p] = TWO_K2E * px[1]; sx20[p] = TWO_K2E * px[2];
            const float* py = y + 3 * (size_t)(base0 + p);
            sy00[p] = TWO_K2E * py[0]; sy10[p] = TWO_K2E * py[1]; sy20[p] = TWO_K2E * py[2];
        }
        {
            const float* px = x + 3 * (size_t)(base1 + p);
            sx01[p] = TWO_K2E * px[0]; sx11[p] = TWO_K2E * px[1]; sx21[p] = TWO_K2E * px[2];
            const float* py = y + 3 * (size_t)(base1 + p);
            sy01[p] = TWO_K2E * py[0]; sy11[p] = TWO_K2E * py[1]; sy21[p] = TWO_K2E * py[2];
        }
    }
    if (tid < 128) {
        const int bb  = tid >> 6;
        const int col = q * 64 + (tid & 63);
        const int bs  = bb ? base1 : base0;
        const float* py = y + 3 * (size_t)(bs + col);
        const float a = py[0], b = py[1], c = py[2];
        DSTORE(&Bf[bs + col], -K2E * (a*a + b*b + c*c));
    }
    __syncthreads();
    if (tid == 0) {
        __hip_atomic_store(f0 + q * 4, 1, __ATOMIC_RELEASE, __HIP_MEMORY_SCOPE_AGENT);
        __hip_atomic_store(f1 + q * 4, 1, __ATOMIC_RELEASE, __HIP_MEMORY_SCOPE_AGENT);
    }

    const int rr = ((lane & 1) << 2) | (lane & 2) | ((lane >> 2) & 1);

    #define PW2(pslot, pval, warr, tgt) do { __syncthreads();                   \
        if (tid == 0)                                                           \
            __hip_atomic_store((pslot), (pval), __ATOMIC_RELEASE,               \
                               __HIP_MEMORY_SCOPE_AGENT);                       \
        if (w == 0) {                                                           \
            for (;;) {                                                          \
                int vv = (lane < 32)                                            \
                    ? __hip_atomic_load((warr) + lane * 4, __ATOMIC_RELAXED,    \
                                        __HIP_MEMORY_SCOPE_AGENT)               \
                    : 0x7fffffff;                                               \
                if (__ballot(vv >= (tgt)) == ~0ULL) break;                      \
                __builtin_amdgcn_s_sleep(1);                                    \
            }                                                                   \
        }                                                                       \
        __syncthreads(); } while (0)

    #define WONLY2(warr, tgt) do { __syncthreads();                             \
        if (w == 0) {                                                           \
            for (;;) {                                                          \
                int vv = (lane < 32)                                            \
                    ? __hip_atomic_load((warr) + lane * 4, __ATOMIC_RELAXED,    \
                                        __HIP_MEMORY_SCOPE_AGENT)               \
                    : 0x7fffffff;                                               \
                if (__ballot(vv >= (tgt)) == ~0ULL) break;                      \
                __builtin_amdgcn_s_sleep(1);                                    \
            }                                                                   \
        }                                                                       \
        __syncthreads(); } while (0)

    WONLY2(f0, 1);

    float Aval0 = 0.f, Aval1 = 0.f;

    for (int it = 0; it < NITERS; ++it) {
        {
            float Sc = sumpassG(sx00, sx10, sx20, sy00, sy10, sy20, Bf + base0,
                                rloc, jh, lane, w, pcomb);
            Aval0 = LMU - __log2f(Sc);
            if (lane < 8 && jh == 0) DSTORE(&Af[base0 + rloc + rr], Aval0);
        }
        PW2(f0 + q * 4, 2 * it + 2, f1, 2 * it + 1);
        {
            float Sc = sumpassG(sx01, sx11, sx21, sy01, sy11, sy21, Bf + base1,
                                rloc, jh, lane, w, pcomb);
            Aval1 = LMU - __log2f(Sc);
            if (lane < 8 && jh == 0) DSTORE(&Af[base1 + rloc + rr], Aval1);
        }
        PW2(f1 + q * 4, 2 * it + 2, f0, 2 * it + 2);
        {
            float Sc = sumpassG(sy00, sy10, sy20, sx00, sx10, sx20, Af + base0,
                                rloc, jh, lane, w, pcomb);
            if (lane < 8 && jh == 0)
                DSTORE(&Bf[base0 + rloc + rr], LMU - __log2f(Sc));
        }
        PW2(f0 + q * 4, 2 * it + 3, f1, 2 * it + 2);
        {
            float Sc = sumpassG(sy01, sy11, sy21, sx01, sx11, sx21, Af + base1,
                                rloc, jh, lane, w, pcomb);
            if (lane < 8 && jh == 0)
                DSTORE(&Bf[base1 + rloc + rr], LMU - __log2f(Sc));
        }
        PW2(f1 + q * 4, 2 * it + 3, f0, 2 * it + 3);
    }
    WONLY2(f1, 2 * NITERS + 1);

    {
        float s = epilG(sx00, sx10, sx20, sy00, sy10, sy20, Bf + base0,
                        Aval0, rloc, jh, lane)
                + epilG(sx01, sx11, sx21, sy01, sy11, sy21, Bf + base1,
                        Aval1, rloc, jh, lane);
        #pragma unroll
        for (int m = 32; m > 0; m >>= 1) s += __shfl_xor(s, m, 64);
        if (lane == 0) wsum[w] = s;
        __syncthreads();
        if (tid == 0) {
            float t = 0.f;
            #pragma unroll
            for (int i = 0; i < 16; ++i) t += wsum[i];
            atomicAdd(out, t * (1.0f / (float)BB));
        }
    }
    #undef PW2
    #undef WONLY2
}

extern "C" void kernel_launch(void* const* d_in, const int* in_sizes, int n_in,
                              void* d_out, int out_size, void* d_ws, size_t ws_size,
                              hipStream_t stream) {
    const float* x = (const float*)d_in[0];
    const float* y = (const float*)d_in[1];
    float* out = (float*)d_out;
    char* ws = (char*)d_ws;

    int*   flags = (int*)ws;                                 // 16 x 32 x 16 B = 8 KB
    float* Af    = (float*)(ws + 8192);                      // 128 KB
    float* Bf    = (float*)(ws + 8192 + (size_t)BB*NN*sizeof(float));

    hipMemsetAsync(flags, 0, 8192, stream);
    hipMemsetAsync(out, 0, sizeof(float), stream);

    void* args[] = {(void*)&x, (void*)&y, (void*)&Af, (void*)&Bf,
                    (void*)&flags, (void*)&out};

    const size_t shmem = (size_t)12 * NN * sizeof(float);    // 96 KB
    hipFuncSetAttribute((const void*)emd_sinkhornF,
                        hipFuncAttributeMaxDynamicSharedMemorySize, (int)shmem);
    hipError_t e = hipLaunchCooperativeKernel((const void*)emd_sinkhornF,
                                              dim3(256), dim3(1024),
                                              args, shmem, stream);
    if (e != hipSuccess) {
        hipFuncSetAttribute((const void*)emd_sinkhorn2,
                            hipFuncAttributeMaxDynamicSharedMemorySize, (int)shmem);
        hipError_t e2 = hipLaunchCooperativeKernel((const void*)emd_sinkhorn2,
                                                   dim3(256), dim3(1024),
                                                   args, shmem, stream);
        if (e2 != hipSuccess) {
            hipLaunchKernelGGL(emd_sinkhorn2, dim3(256), dim3(1024), shmem,
                               stream, x, y, Af, Bf, flags, out);
        }
    }
}